// Round 3
// baseline (2039.001 us; speedup 1.0000x reference)
//
#include <hip/hip_runtime.h>
#include <cstdint>
#include <cstddef>

#define TT 20
#define BB 262144

// f64 weight scratch layout (element offsets, in doubles):
//   W1T [10][64] @ 0       (W1T[k][o] = W1[o][k])
//   W2T [64][32] @ 640
//   W3T [32][32] @ 2688
//   W4T [32][16] @ 3712
//   W5T [16][6]  @ 4224    total 4320 doubles = 34560 B
#define OFF_W2T 640
#define OFF_W3T 2688
#define OFF_W4T 3712
#define OFF_W5T 4224
#define W_TOTAL 4320

// workspace layout (bytes) — total 62,949,376 B, identical to R2's proven budget.
//   Wd   @ 0          (34560 B, padded to 34816)
//   P1   @ 34816      u16[4][TT][BB] = 41,943,040 B   (l1 spikes, 16 bits/part)
//   P2   @ 41977856   u16[2][TT][BB] = 20,971,520 B   (l2 spikes)
//   P3   aliases P1   u16[2][TT][BB]                  (l3 spikes; l1 data dead)
//   P4   aliases P2   u8 [2][TT][BB]                  (l4 spikes; l2 data dead)
#define WS_MASK_BASE 34816
#define P1_BYTES (4 * (size_t)TT * BB * 2)
#define P2_OFFSET (WS_MASK_BASE + P1_BYTES)
#define P2_BYTES (2 * (size_t)TT * BB * 2)
#define WS_NEEDED (P2_OFFSET + P2_BYTES)
#define PLANE ((size_t)TT * BB)

__global__ void prep_weights(const float* __restrict__ W1, const float* __restrict__ W2,
                             const float* __restrict__ W3, const float* __restrict__ W4,
                             const float* __restrict__ W5, double* __restrict__ Wd) {
  int stride = blockDim.x * gridDim.x;
  for (int idx = blockIdx.x * blockDim.x + threadIdx.x; idx < W_TOTAL; idx += stride) {
    double v;
    if (idx < OFF_W2T) {
      int j = idx;            int k = j / 64, o = j % 64; v = (double)W1[o * 10 + k];
    } else if (idx < OFF_W3T) {
      int j = idx - OFF_W2T;  int k = j / 32, o = j % 32; v = (double)W2[o * 64 + k];
    } else if (idx < OFF_W4T) {
      int j = idx - OFF_W3T;  int k = j / 32, o = j % 32; v = (double)W3[o * 32 + k];
    } else if (idx < OFF_W5T) {
      int j = idx - OFF_W4T;  int k = j / 16, o = j % 16; v = (double)W4[o * 32 + k];
    } else {
      int j = idx - OFF_W5T;  int k = j / 6,  o = j % 6;  v = (double)W5[o * 16 + k];
    }
    Wd[idx] = v;
  }
}

// Layer 1 (10 -> 64): 4 parts x 16 outputs. grid 4096. part in LOW bits of
// blockIdx so the 4 sibling blocks reading the same x stream run adjacently
// (L2-shared). VGPR ~60; lb(256,4) to avoid forced spills.
__global__ __launch_bounds__(256, 4) void snn_l1(const float* __restrict__ x,
                                                 const double* __restrict__ Wd,
                                                 uint16_t* __restrict__ P1) {
  const int part = blockIdx.x & 3;
  const int e = (blockIdx.x >> 2) * 256 + threadIdx.x;
  const double* __restrict__ W1T = Wd + part * 16;
  uint16_t* __restrict__ dst = P1 + (size_t)part * PLANE + e;

  double m[16];
#pragma unroll
  for (int o = 0; o < 16; ++o) m[o] = 0.0;

#pragma unroll 1
  for (int t = 0; t < TT; ++t) {
    const float* xp = x + ((size_t)t * BB + e) * 10;
    float xv[10];
#pragma unroll
    for (int i = 0; i < 5; ++i) {
      float2 f = ((const float2*)xp)[i];
      xv[2 * i] = f.x; xv[2 * i + 1] = f.y;
    }
#pragma unroll
    for (int o = 0; o < 16; ++o) {
      double sub = (m[o] > 1.0) ? 1.0 : 0.0;
      m[o] = 0.9 * m[o] - sub;
    }
#pragma unroll
    for (int k = 0; k < 10; ++k) {
      double s = (double)xv[k];
      const double* col = W1T + k * 64;
#pragma unroll
      for (int o = 0; o < 16; ++o) m[o] = fma(s, col[o], m[o]);
    }
    uint32_t msk = 0u;
#pragma unroll
    for (int o = 0; o < 16; ++o) msk |= (m[o] > 1.0) ? (1u << o) : 0u;
    dst[(size_t)t * BB] = (uint16_t)msk;
  }
}

// Layer 2 (64 -> 32): 2 parts x 16 outputs. grid 2048 -> 8 waves/SIMD.
// State 32 VGPR -> lb(256,8) targets the <=64-VGPR occupancy tier.
__global__ __launch_bounds__(256, 8) void snn_l2(const double* __restrict__ Wd,
                                                 const uint16_t* __restrict__ P1,
                                                 uint16_t* __restrict__ P2) {
  const int part = blockIdx.x & 1;
  const int e = (blockIdx.x >> 1) * 256 + threadIdx.x;
  const double* __restrict__ W2T = Wd + OFF_W2T + part * 16;
  const uint16_t* __restrict__ src = P1 + e;
  uint16_t* __restrict__ dst = P2 + (size_t)part * PLANE + e;

  double m[16];
#pragma unroll
  for (int o = 0; o < 16; ++o) m[o] = 0.0;

#pragma unroll 1
  for (int t = 0; t < TT; ++t) {
    const size_t off = (size_t)t * BB;
    uint32_t blo = (uint32_t)src[off] | ((uint32_t)src[off + PLANE] << 16);
    uint32_t bhi = (uint32_t)src[off + 2 * PLANE] | ((uint32_t)src[off + 3 * PLANE] << 16);
#pragma unroll
    for (int o = 0; o < 16; ++o) {
      double sub = (m[o] > 1.0) ? 1.0 : 0.0;
      m[o] = 0.9 * m[o] - sub;
    }
    {
      const double* col = W2T;
      uint32_t b = blo;
      for (int k = 0; k < 32; ++k) {
        double s = (double)(b & 1u);
        b >>= 1;
#pragma unroll
        for (int o = 0; o < 16; ++o) m[o] = fma(s, col[o], m[o]);
        col += 32;
      }
      b = bhi;
      for (int k = 0; k < 32; ++k) {
        double s = (double)(b & 1u);
        b >>= 1;
#pragma unroll
        for (int o = 0; o < 16; ++o) m[o] = fma(s, col[o], m[o]);
        col += 32;
      }
    }
    uint32_t msk = 0u;
#pragma unroll
    for (int o = 0; o < 16; ++o) msk |= (m[o] > 1.0) ? (1u << o) : 0u;
    dst[off] = (uint16_t)msk;
  }
}

// Layer 3 (32 -> 32): 2 parts x 16 outputs. grid 2048.
__global__ __launch_bounds__(256, 8) void snn_l3(const double* __restrict__ Wd,
                                                 const uint16_t* __restrict__ P2,
                                                 uint16_t* __restrict__ P3) {
  const int part = blockIdx.x & 1;
  const int e = (blockIdx.x >> 1) * 256 + threadIdx.x;
  const double* __restrict__ W3T = Wd + OFF_W3T + part * 16;
  const uint16_t* __restrict__ src = P2 + e;
  uint16_t* __restrict__ dst = P3 + (size_t)part * PLANE + e;

  double m[16];
#pragma unroll
  for (int o = 0; o < 16; ++o) m[o] = 0.0;

#pragma unroll 1
  for (int t = 0; t < TT; ++t) {
    const size_t off = (size_t)t * BB;
    uint32_t bits = (uint32_t)src[off] | ((uint32_t)src[off + PLANE] << 16);
#pragma unroll
    for (int o = 0; o < 16; ++o) {
      double sub = (m[o] > 1.0) ? 1.0 : 0.0;
      m[o] = 0.9 * m[o] - sub;
    }
    {
      const double* col = W3T;
      uint32_t b = bits;
      for (int k = 0; k < 32; ++k) {
        double s = (double)(b & 1u);
        b >>= 1;
#pragma unroll
        for (int o = 0; o < 16; ++o) m[o] = fma(s, col[o], m[o]);
        col += 32;
      }
    }
    uint32_t msk = 0u;
#pragma unroll
    for (int o = 0; o < 16; ++o) msk |= (m[o] > 1.0) ? (1u << o) : 0u;
    dst[off] = (uint16_t)msk;
  }
}

// Layer 4 (32 -> 16): 2 parts x 8 outputs. grid 2048.
__global__ __launch_bounds__(256, 8) void snn_l4(const double* __restrict__ Wd,
                                                 const uint16_t* __restrict__ P3,
                                                 uint8_t* __restrict__ P4) {
  const int part = blockIdx.x & 1;
  const int e = (blockIdx.x >> 1) * 256 + threadIdx.x;
  const double* __restrict__ W4T = Wd + OFF_W4T + part * 8;
  const uint16_t* __restrict__ src = P3 + e;
  uint8_t* __restrict__ dst = P4 + (size_t)part * PLANE + e;

  double m[8];
#pragma unroll
  for (int o = 0; o < 8; ++o) m[o] = 0.0;

#pragma unroll 1
  for (int t = 0; t < TT; ++t) {
    const size_t off = (size_t)t * BB;
    uint32_t bits = (uint32_t)src[off] | ((uint32_t)src[off + PLANE] << 16);
#pragma unroll
    for (int o = 0; o < 8; ++o) {
      double sub = (m[o] > 1.0) ? 1.0 : 0.0;
      m[o] = 0.9 * m[o] - sub;
    }
    {
      const double* col = W4T;
      uint32_t b = bits;
      for (int k = 0; k < 32; ++k) {
        double s = (double)(b & 1u);
        b >>= 1;
#pragma unroll
        for (int o = 0; o < 8; ++o) m[o] = fma(s, col[o], m[o]);
        col += 16;
      }
    }
    uint32_t msk = 0u;
#pragma unroll
    for (int o = 0; o < 8; ++o) msk |= (m[o] > 1.0) ? (1u << o) : 0u;
    dst[off] = (uint8_t)msk;
  }
}

// Layer 5 (16 -> 6): one thread per element. grid 1024 (small kernel, ~13 us ideal).
__global__ __launch_bounds__(256, 8) void snn_l5(const double* __restrict__ Wd,
                                                 const uint8_t* __restrict__ P4,
                                                 float* __restrict__ out) {
  const int e = blockIdx.x * 256 + threadIdx.x;
  const double* __restrict__ W5T = Wd + OFF_W5T;
  const uint8_t* __restrict__ src = P4 + e;

  double m[6];
#pragma unroll
  for (int o = 0; o < 6; ++o) m[o] = 0.0;

#pragma unroll 1
  for (int t = 0; t < TT; ++t) {
    const size_t off = (size_t)t * BB;
    uint32_t bits = (uint32_t)src[off] | ((uint32_t)src[off + PLANE] << 8);
#pragma unroll
    for (int o = 0; o < 6; ++o) {
      double sub = (m[o] > 1.0) ? 1.0 : 0.0;
      m[o] = 0.9 * m[o] - sub;
    }
    {
      const double* col = W5T;
      uint32_t b = bits;
      for (int k = 0; k < 16; ++k) {
        double s = (double)(b & 1u);
        b >>= 1;
#pragma unroll
        for (int o = 0; o < 6; ++o) m[o] = fma(s, col[o], m[o]);
        col += 6;
      }
    }
    float ov[6];
#pragma unroll
    for (int o = 0; o < 6; ++o) ov[o] = (m[o] > 1.0) ? 1.0f : 0.0f;
    float* op = out + ((size_t)t * BB + e) * 6;
    ((float2*)op)[0] = make_float2(ov[0], ov[1]);
    ((float2*)op)[1] = make_float2(ov[2], ov[3]);
    ((float2*)op)[2] = make_float2(ov[4], ov[5]);
  }
}

// ---------------- fallback: round-1 monolithic kernel (ws too small) ----------------

__global__ __launch_bounds__(256, 1) void snn_f64(const float* __restrict__ x,
                                                  const double* __restrict__ Wd,
                                                  float* __restrict__ out) {
  const int e = blockIdx.x * blockDim.x + threadIdx.x;
  const double* __restrict__ W1T = Wd;
  const double* __restrict__ W2T = Wd + OFF_W2T;
  const double* __restrict__ W3T = Wd + OFF_W3T;
  const double* __restrict__ W4T = Wd + OFF_W4T;
  const double* __restrict__ W5T = Wd + OFF_W5T;

  double m1[64], m2[32], m3[32], m4[16], m5[6];
#pragma unroll
  for (int o = 0; o < 64; ++o) m1[o] = 0.0;
#pragma unroll
  for (int o = 0; o < 32; ++o) m2[o] = 0.0;
#pragma unroll
  for (int o = 0; o < 32; ++o) m3[o] = 0.0;
#pragma unroll
  for (int o = 0; o < 16; ++o) m4[o] = 0.0;
#pragma unroll
  for (int o = 0; o < 6; ++o) m5[o] = 0.0;

#pragma unroll 1
  for (int t = 0; t < TT; ++t) {
    const float* xp = x + ((size_t)t * BB + e) * 10;
    float xv[10];
#pragma unroll
    for (int i = 0; i < 5; ++i) {
      float2 f = ((const float2*)xp)[i];
      xv[2 * i] = f.x; xv[2 * i + 1] = f.y;
    }
#pragma unroll
    for (int o = 0; o < 64; ++o) {
      double sub = (m1[o] > 1.0) ? 1.0 : 0.0;
      m1[o] = 0.9 * m1[o] - sub;
    }
#pragma unroll
    for (int k = 0; k < 10; ++k) {
      double s = (double)xv[k];
      const double* col = W1T + k * 64;
#pragma unroll
      for (int o = 0; o < 64; ++o) m1[o] = fma(s, col[o], m1[o]);
    }
    unsigned long long msk1 = 0ull;
#pragma unroll
    for (int o = 0; o < 64; ++o) msk1 |= (m1[o] > 1.0) ? (1ull << o) : 0ull;

#pragma unroll
    for (int o = 0; o < 32; ++o) {
      double sub = (m2[o] > 1.0) ? 1.0 : 0.0;
      m2[o] = 0.9 * m2[o] - sub;
    }
    {
      unsigned long long m = msk1;
      const double* col = W2T;
      for (int k = 0; k < 64; ++k) {
        double s = (double)(unsigned int)(m & 1ull);
        m >>= 1;
#pragma unroll
        for (int o = 0; o < 32; ++o) m2[o] = fma(s, col[o], m2[o]);
        col += 32;
      }
    }
    unsigned int msk2 = 0u;
#pragma unroll
    for (int o = 0; o < 32; ++o) msk2 |= (m2[o] > 1.0) ? (1u << o) : 0u;

#pragma unroll
    for (int o = 0; o < 32; ++o) {
      double sub = (m3[o] > 1.0) ? 1.0 : 0.0;
      m3[o] = 0.9 * m3[o] - sub;
    }
    {
      unsigned int m = msk2;
      const double* col = W3T;
      for (int k = 0; k < 32; ++k) {
        double s = (double)(m & 1u);
        m >>= 1;
#pragma unroll
        for (int o = 0; o < 32; ++o) m3[o] = fma(s, col[o], m3[o]);
        col += 32;
      }
    }
    unsigned int msk3 = 0u;
#pragma unroll
    for (int o = 0; o < 32; ++o) msk3 |= (m3[o] > 1.0) ? (1u << o) : 0u;

#pragma unroll
    for (int o = 0; o < 16; ++o) {
      double sub = (m4[o] > 1.0) ? 1.0 : 0.0;
      m4[o] = 0.9 * m4[o] - sub;
    }
    {
      unsigned int m = msk3;
      const double* col = W4T;
      for (int k = 0; k < 32; ++k) {
        double s = (double)(m & 1u);
        m >>= 1;
#pragma unroll
        for (int o = 0; o < 16; ++o) m4[o] = fma(s, col[o], m4[o]);
        col += 16;
      }
    }
    unsigned int msk4 = 0u;
#pragma unroll
    for (int o = 0; o < 16; ++o) msk4 |= (m4[o] > 1.0) ? (1u << o) : 0u;

#pragma unroll
    for (int o = 0; o < 6; ++o) {
      double sub = (m5[o] > 1.0) ? 1.0 : 0.0;
      m5[o] = 0.9 * m5[o] - sub;
    }
    {
      unsigned int m = msk4;
      const double* col = W5T;
      for (int k = 0; k < 16; ++k) {
        double s = (double)(m & 1u);
        m >>= 1;
#pragma unroll
        for (int o = 0; o < 6; ++o) m5[o] = fma(s, col[o], m5[o]);
        col += 6;
      }
    }

    float ov[6];
#pragma unroll
    for (int o = 0; o < 6; ++o) ov[o] = (m5[o] > 1.0) ? 1.0f : 0.0f;
    float* op = out + ((size_t)t * BB + e) * 6;
    ((float2*)op)[0] = make_float2(ov[0], ov[1]);
    ((float2*)op)[1] = make_float2(ov[2], ov[3]);
    ((float2*)op)[2] = make_float2(ov[4], ov[5]);
  }
}

extern "C" void kernel_launch(void* const* d_in, const int* in_sizes, int n_in,
                              void* d_out, int out_size, void* d_ws, size_t ws_size,
                              hipStream_t stream) {
  const float* x  = (const float*)d_in[0];
  const float* W1 = (const float*)d_in[1];
  const float* W2 = (const float*)d_in[2];
  const float* W3 = (const float*)d_in[3];
  const float* W4 = (const float*)d_in[4];
  const float* W5 = (const float*)d_in[5];
  float* out = (float*)d_out;
  double* Wd = (double*)d_ws;

  prep_weights<<<17, 256, 0, stream>>>(W1, W2, W3, W4, W5, Wd);

  if (ws_size >= WS_NEEDED) {
    char* base = (char*)d_ws;
    uint16_t* P1 = (uint16_t*)(base + WS_MASK_BASE);
    uint16_t* P2 = (uint16_t*)(base + P2_OFFSET);
    uint16_t* P3 = (uint16_t*)(base + WS_MASK_BASE);  // aliases P1 (l1 data dead after l2)
    uint8_t*  P4 = (uint8_t*)(base + P2_OFFSET);      // aliases P2 (l2 data dead after l3)
    snn_l1<<<4096, 256, 0, stream>>>(x, Wd, P1);
    snn_l2<<<2048, 256, 0, stream>>>(Wd, P1, P2);
    snn_l3<<<2048, 256, 0, stream>>>(Wd, P2, P3);
    snn_l4<<<2048, 256, 0, stream>>>(Wd, P3, P4);
    snn_l5<<<1024, 256, 0, stream>>>(Wd, P4, out);
  } else {
    snn_f64<<<BB / 256, 256, 0, stream>>>(x, Wd, out);
  }
}